// Round 1
// baseline (425.199 us; speedup 1.0000x reference)
//
#include <hip/hip_runtime.h>
#include <math.h>

typedef unsigned short u16;
typedef unsigned int   u32;
typedef __attribute__((ext_vector_type(4))) float f32x4;
typedef __attribute__((ext_vector_type(4))) u16   u16x4;
typedef __attribute__((ext_vector_type(8))) __bf16 bf16x8;

__device__ __forceinline__ u16 f2bf(float f) {
  u32 u = __builtin_bit_cast(u32, f);
  u += 0x7fffu + ((u >> 16) & 1u);   // round-to-nearest-even
  return (u16)(u >> 16);
}

// ---------------- cast f32 -> bf16 (vectorized) ----------------
__global__ void cast_f32_to_bf16(const float* __restrict__ in, u16* __restrict__ out, int n4) {
  int i = blockIdx.x * 256 + threadIdx.x;
  if (i >= n4) return;
  f32x4 v = *(const f32x4*)(in + (long)i * 4);
  u16x4 o = { f2bf(v[0]), f2bf(v[1]), f2bf(v[2]), f2bf(v[3]) };
  *(u16x4*)(out + (long)i * 4) = o;
}

// ---------------- generic batched NT GEMM, bf16 MFMA ----------------
// C[m,n] = scale * sum_k A[m,k]*B[n,k] + bias[n]
// 128x128 tile, BK=64, 256 threads = 4 waves (2x2), 16x16x32 bf16 MFMA.
// EPI: 0 f32 row-major; 1 bf16 row-major; 2 bf16 (B,S,H*128)->(B,H,S,128);
//      3 bf16 (B,S,H*128)->(B,H,128,S) transposed; 4 bf16 ctx (batched bz=b*16+h)
// AF32: A operand is f32 in global (converted to bf16 during LDS staging)
template<int EPI, bool AF32>
__launch_bounds__(256, 2)
__global__ void gemm_nt(const void* __restrict__ Av, const u16* __restrict__ Bg,
                        const float* __restrict__ bias, void* __restrict__ Cout,
                        int M, int N, int K, int lda, int ldb, int ldc,
                        int batchA, int batchB, int batchC, float scale)
{
  __shared__ __align__(16) u16 As[128 * 64];
  __shared__ __align__(16) u16 Bs[128 * 64];
  const int tid  = threadIdx.x;
  const int lane = tid & 63;
  const int wid  = tid >> 6;
  const int wm = wid >> 1, wn = wid & 1;
  const int lr = lane & 15, lg = lane >> 4;
  const int m0 = blockIdx.y * 128, n0 = blockIdx.x * 128;
  const int bz = blockIdx.z;

  const u16*   Ab = (const u16*)Av   + (long)bz * batchA;   // used iff !AF32
  const float* Af = (const float*)Av + (long)bz * batchA;   // used iff AF32
  const u16*   Bb = Bg + (long)bz * batchB;

  f32x4 acc[4][4] = {};

  for (int k0 = 0; k0 < K; k0 += 64) {
    if (!AF32) {
      #pragma unroll
      for (int i = 0; i < 4; ++i) {
        const int eo = (wid * 64 + lane) * 8 + i * 2048;  // element offset in 128x64 tile
        const int r = eo >> 6, c = eo & 63;
        __builtin_amdgcn_global_load_lds(
            (const __attribute__((address_space(1))) void*)(Ab + (long)(m0 + r) * lda + (k0 + c)),
            (__attribute__((address_space(3))) void*)(As + wid * 512 + i * 2048),
            16, 0, 0);
      }
    } else {
      #pragma unroll
      for (int i = 0; i < 8; ++i) {
        const int idx = tid + i * 256;                    // float4 units, 2048 total
        const int r = idx >> 4, c = (idx & 15) * 4;
        f32x4 v = *(const f32x4*)(Af + (long)(m0 + r) * lda + (k0 + c));
        u16x4 o = { f2bf(v[0]), f2bf(v[1]), f2bf(v[2]), f2bf(v[3]) };
        *(u16x4*)(As + r * 64 + c) = o;
      }
    }
    #pragma unroll
    for (int i = 0; i < 4; ++i) {
      const int eo = (wid * 64 + lane) * 8 + i * 2048;
      const int r = eo >> 6, c = eo & 63;
      __builtin_amdgcn_global_load_lds(
          (const __attribute__((address_space(1))) void*)(Bb + (long)(n0 + r) * ldb + (k0 + c)),
          (__attribute__((address_space(3))) void*)(Bs + wid * 512 + i * 2048),
          16, 0, 0);
    }
    __syncthreads();
    #pragma unroll
    for (int kk = 0; kk < 64; kk += 32) {
      bf16x8 a4[4], b4[4];
      #pragma unroll
      for (int f = 0; f < 4; ++f)
        a4[f] = *(const bf16x8*)(As + (wm * 64 + f * 16 + lr) * 64 + kk + lg * 8);
      #pragma unroll
      for (int f = 0; f < 4; ++f)
        b4[f] = *(const bf16x8*)(Bs + (wn * 64 + f * 16 + lr) * 64 + kk + lg * 8);
      #pragma unroll
      for (int i = 0; i < 4; ++i)
        #pragma unroll
        for (int j = 0; j < 4; ++j)
          acc[i][j] = __builtin_amdgcn_mfma_f32_16x16x32_bf16(a4[i], b4[j], acc[i][j], 0, 0, 0);
    }
    __syncthreads();
  }

  // epilogue: lane holds C[row = (lane>>4)*4 + r][col = lane&15] per 16x16 frag
  #pragma unroll
  for (int i = 0; i < 4; ++i) {
    const int mB = m0 + wm * 64 + i * 16 + lg * 4;
    #pragma unroll
    for (int j = 0; j < 4; ++j) {
      const int nn = n0 + wn * 64 + j * 16 + lr;
      const float bs = bias ? bias[nn] : 0.0f;
      #pragma unroll
      for (int r = 0; r < 4; ++r) {
        const int m = mB + r;
        const float v = acc[i][j][r] * scale + bs;
        if (EPI == 0) {
          ((float*)Cout)[(long)bz * batchC + (long)m * ldc + nn] = v;
        } else if (EPI == 1) {
          ((u16*)Cout)[(long)bz * batchC + (long)m * ldc + nn] = f2bf(v);
        } else if (EPI == 2) { // (B,S,H*128) -> (B,H,S,128)
          const int b = m >> 9, s = m & 511, h = nn >> 7, d = nn & 127;
          ((u16*)Cout)[(((long)(b * 16 + h) * 512 + s) << 7) + d] = f2bf(v);
        } else if (EPI == 3) { // (B,S,H*128) -> (B,H,128,S)
          const int b = m >> 9, s = m & 511, h = nn >> 7, d = nn & 127;
          ((u16*)Cout)[(((long)(b * 16 + h) * 128 + d) << 9) + s] = f2bf(v);
        } else {               // 4: ctx, bz=b*16+h, m=q row, nn=d -> (B,S,H*128)
          const int b = bz >> 4, h = bz & 15;
          ((u16*)Cout)[(long)(b * 512 + m) * 2048 + h * 128 + nn] = f2bf(v);
        }
      }
    }
  }
}

// ---------------- rope: read raw (4096 x 1024 f32), write bf16 into k_ws dims 0..63 ----------------
__global__ void rope_apply(const float* __restrict__ raw, u16* __restrict__ kws) {
  const int idx = blockIdx.x * 256 + threadIdx.x;   // < 4096*512
  const int i   = idx & 31;
  const int h   = (idx >> 5) & 15;
  const int row = idx >> 9;          // b*512 + s
  const int s   = row & 511;
  const int b   = row >> 9;
  const float x1 = raw[(long)row * 1024 + h * 64 + i];
  const float x2 = raw[(long)row * 1024 + h * 64 + 32 + i];
  const float invf = __powf(10000.0f, -(float)i * (1.0f / 32.0f));
  const float ang  = (float)s * invf;
  float sn, cs;
  __sincosf(ang, &sn, &cs);
  const long base = ((long)(b * 16 + h) * 512 + s) * 128;
  kws[base + i]      = f2bf(x1 * cs - x2 * sn);
  kws[base + 32 + i] = f2bf(x2 * cs + x1 * sn);
}

// ---------------- softmax: one wave per row of 512 f32, in-place ----------------
__global__ void softmax_rows(float* __restrict__ attn, int nrows) {
  const int gw = (blockIdx.x * 256 + threadIdx.x) >> 6;
  if (gw >= nrows) return;
  const int lane = threadIdx.x & 63;
  float* row = attn + (long)gw * 512;
  f32x4 a = *(const f32x4*)(row + lane * 4);
  f32x4 b = *(const f32x4*)(row + 256 + lane * 4);
  float mx = fmaxf(fmaxf(fmaxf(a[0], a[1]), fmaxf(a[2], a[3])),
                   fmaxf(fmaxf(b[0], b[1]), fmaxf(b[2], b[3])));
  #pragma unroll
  for (int off = 32; off; off >>= 1) mx = fmaxf(mx, __shfl_xor(mx, off));
  float sum = 0.f;
  #pragma unroll
  for (int t = 0; t < 4; ++t) { a[t] = __expf(a[t] - mx); sum += a[t]; }
  #pragma unroll
  for (int t = 0; t < 4; ++t) { b[t] = __expf(b[t] - mx); sum += b[t]; }
  #pragma unroll
  for (int off = 32; off; off >>= 1) sum += __shfl_xor(sum, off);
  const float inv = 1.0f / sum;
  a *= inv; b *= inv;
  *(f32x4*)(row + lane * 4) = a;
  *(f32x4*)(row + 256 + lane * 4) = b;
}

extern "C" void kernel_launch(void* const* d_in, const int* in_sizes, int n_in,
                              void* d_out, int out_size, void* d_ws, size_t ws_size,
                              hipStream_t stream)
{
  (void)in_sizes; (void)n_in; (void)out_size; (void)ws_size;
  const float* query  = (const float*)d_in[0];
  const float* kvin   = (const float*)d_in[1];
  const float* wq_w   = (const float*)d_in[2];
  const float* wq_b   = (const float*)d_in[3];
  const float* wdkv_w = (const float*)d_in[4];
  const float* wdkv_b = (const float*)d_in[5];
  const float* wupk_w = (const float*)d_in[6];
  const float* wupk_b = (const float*)d_in[7];
  const float* wupv_w = (const float*)d_in[8];
  const float* wupv_b = (const float*)d_in[9];
  const float* wkr_w  = (const float*)d_in[10];
  const float* wkr_b  = (const float*)d_in[11];
  const float* wo_w   = (const float*)d_in[12];
  const float* wo_b   = (const float*)d_in[13];

  float* out  = (float*)d_out;                 // (8,512,2048)
  float* attn = out + 8L * 512 * 2048;         // (8,16,512,512)

  u16* p = (u16*)d_ws;
  u16* query_bf = p; p += 8388608;
  u16* kv_bf    = p; p += 8388608;
  u16* wq_bf    = p; p += 4194304;
  u16* wdkv_bf  = p; p += 1048576;
  u16* wupk_bf  = p; p += 1048576;
  u16* wupv_bf  = p; p += 1048576;
  u16* wkr_bf   = p; p += 2097152;
  u16* wo_bf    = p; p += 4194304;
  u16* q_ws     = p; p += 8388608;   // (B,H,S,128) bf16
  u16* ckv_bf   = p; p += 2097152;   // (4096,512) bf16
  u16* k_ws     = p; p += 8388608;   // (B,H,S,128) bf16
  u16* vT_ws    = p; p += 8388608;   // (B,H,128,S) bf16
  u16* ctx_ws   = p; p += 8388608;   // (B,S,H*128) bf16
  float* rope_raw = (float*)p;       // (4096,1024) f32

  auto cast = [&](const float* src, u16* dst, int n) {
    int n4 = n >> 2;
    cast_f32_to_bf16<<<dim3((n4 + 255) / 256), dim3(256), 0, stream>>>(src, dst, n4);
  };
  cast(query,  query_bf, 8388608);
  cast(kvin,   kv_bf,    8388608);
  cast(wq_w,   wq_bf,    4194304);
  cast(wdkv_w, wdkv_bf,  1048576);
  cast(wupk_w, wupk_bf,  1048576);
  cast(wupv_w, wupv_bf,  1048576);
  cast(wkr_w,  wkr_bf,   2097152);
  cast(wo_w,   wo_bf,    4194304);

  // c_kv = kv @ wdkv^T + b  -> bf16 (4096,512)
  gemm_nt<1,false><<<dim3(4, 32, 1), 256, 0, stream>>>(kv_bf, wdkv_bf, wdkv_b, ckv_bf,
      4096, 512, 2048, 2048, 2048, 512, 0, 0, 0, 1.0f);
  // k_up = c_kv @ wupk^T + b -> k_ws head-major
  gemm_nt<2,false><<<dim3(16, 32, 1), 256, 0, stream>>>(ckv_bf, wupk_bf, wupk_b, k_ws,
      4096, 2048, 512, 512, 512, 0, 0, 0, 0, 1.0f);
  // v_up = c_kv @ wupv^T + b -> vT_ws head-major transposed
  gemm_nt<3,false><<<dim3(16, 32, 1), 256, 0, stream>>>(ckv_bf, wupv_bf, wupv_b, vT_ws,
      4096, 2048, 512, 512, 512, 0, 0, 0, 0, 1.0f);
  // k_rope raw = kv @ wkr^T + b -> f32 (4096,1024)
  gemm_nt<0,false><<<dim3(8, 32, 1), 256, 0, stream>>>(kv_bf, wkr_bf, wkr_b, rope_raw,
      4096, 1024, 2048, 2048, 2048, 1024, 0, 0, 0, 1.0f);
  // rope -> overwrite k_ws dims 0..63 per head
  rope_apply<<<dim3(8192), dim3(256), 0, stream>>>(rope_raw, k_ws);
  // q = query @ wq^T + b -> q_ws head-major
  gemm_nt<2,false><<<dim3(16, 32, 1), 256, 0, stream>>>(query_bf, wq_bf, wq_b, q_ws,
      4096, 2048, 2048, 2048, 2048, 0, 0, 0, 0, 1.0f);
  // scores = (q k^T)/sqrt(128), batched over 128 (b,h) -> attn region (f32, raw)
  gemm_nt<0,false><<<dim3(4, 4, 128), 256, 0, stream>>>(q_ws, k_ws, nullptr, attn,
      512, 512, 128, 128, 128, 512, 65536, 65536, 262144, 0.08838834764831845f);
  // softmax rows in place
  softmax_rows<<<dim3(16384), dim3(256), 0, stream>>>(attn, 65536);
  // ctx = P @ V  (A = f32 attn, B = vT) -> ctx_ws (B,S,H*128) bf16
  gemm_nt<4,true><<<dim3(1, 4, 128), 256, 0, stream>>>(attn, vT_ws, nullptr, ctx_ws,
      512, 128, 512, 512, 512, 0, 262144, 65536, 0, 1.0f);
  // out = ctx @ wo^T + b -> f32 (8,512,2048)
  gemm_nt<0,false><<<dim3(16, 32, 1), 256, 0, stream>>>(ctx_ws, wo_bf, wo_b, out,
      4096, 2048, 2048, 2048, 2048, 2048, 0, 0, 0, 1.0f);
}

// Round 2
// 382.656 us; speedup vs baseline: 1.1112x; 1.1112x over previous
//
#include <hip/hip_runtime.h>
#include <math.h>

typedef unsigned short u16;
typedef unsigned int   u32;
typedef __attribute__((ext_vector_type(4))) float f32x4;
typedef __attribute__((ext_vector_type(4))) u16   u16x4;
typedef __attribute__((ext_vector_type(8))) __bf16 bf16x8;

#define AS1 __attribute__((address_space(1)))
#define AS3 __attribute__((address_space(3)))

__device__ __forceinline__ u16 f2bf(float f) {
  u32 u = __builtin_bit_cast(u32, f);
  u += 0x7fffu + ((u >> 16) & 1u);   // round-to-nearest-even
  return (u16)(u >> 16);
}

// ---------------- cast f32 -> bf16 (vectorized) ----------------
__global__ void cast_f32_to_bf16(const float* __restrict__ in, u16* __restrict__ out, int n4) {
  int i = blockIdx.x * 256 + threadIdx.x;
  if (i >= n4) return;
  f32x4 v = *(const f32x4*)(in + (long)i * 4);
  u16x4 o = { f2bf(v[0]), f2bf(v[1]), f2bf(v[2]), f2bf(v[3]) };
  *(u16x4*)(out + (long)i * 4) = o;
}

// ---------------- generic batched NT GEMM, bf16 MFMA ----------------
// C[m,n] = scale * sum_k A[m,k]*B[n,k] + bias[n]
// EPI: 0 f32 row-major; 1 bf16 row-major;
//      2 bf16 (B,S,H*128)->(B,H,S,128) with XOR-swizzled d;
//      3 bf16 (B,S,H*128)->(B,H,128,S) transposed, XOR-swizzled s;
//      5 bf16 k-half: N=1024, B-row remap h*128+64+(n&63), write d=64.. swizzled
template<int EPI>
__launch_bounds__(256, 2)
__global__ void gemm_nt(const u16* __restrict__ Ag, const u16* __restrict__ Bg,
                        const float* __restrict__ bias, void* __restrict__ Cout,
                        int M, int N, int K, int lda, int ldb, int ldc,
                        int batchA, int batchB, int batchC, float scale)
{
  __shared__ __align__(16) u16 As[128 * 64];
  __shared__ __align__(16) u16 Bs[128 * 64];
  const int tid  = threadIdx.x;
  const int lane = tid & 63;
  const int wid  = tid >> 6;
  const int wm = wid >> 1, wn = wid & 1;
  const int lr = lane & 15, lg = lane >> 4;
  const int m0 = blockIdx.y * 128, n0 = blockIdx.x * 128;
  const int bz = blockIdx.z;

  const u16* Ab = Ag + (long)bz * batchA;
  const u16* Bb = Bg + (long)bz * batchB;

  f32x4 acc[4][4] = {};

  for (int k0 = 0; k0 < K; k0 += 64) {
    #pragma unroll
    for (int i = 0; i < 4; ++i) {
      const int eo = (wid * 64 + lane) * 8 + i * 2048;  // element offset in 128x64 tile
      const int r = eo >> 6, c = eo & 63;
      __builtin_amdgcn_global_load_lds(
          (const AS1 void*)(Ab + (long)(m0 + r) * lda + (k0 + c)),
          (AS3 void*)(As + wid * 512 + i * 2048), 16, 0, 0);
    }
    #pragma unroll
    for (int i = 0; i < 4; ++i) {
      const int eo = (wid * 64 + lane) * 8 + i * 2048;
      const int r = eo >> 6, c = eo & 63;
      int nrow = n0 + r;
      if (EPI == 5) nrow = ((nrow >> 6) << 7) + 64 + (nrow & 63);
      __builtin_amdgcn_global_load_lds(
          (const AS1 void*)(Bb + (long)nrow * ldb + (k0 + c)),
          (AS3 void*)(Bs + wid * 512 + i * 2048), 16, 0, 0);
    }
    __syncthreads();
    #pragma unroll
    for (int kk = 0; kk < 64; kk += 32) {
      bf16x8 a4[4], b4[4];
      #pragma unroll
      for (int f = 0; f < 4; ++f)
        a4[f] = *(const bf16x8*)(As + (wm * 64 + f * 16 + lr) * 64 + kk + lg * 8);
      #pragma unroll
      for (int f = 0; f < 4; ++f)
        b4[f] = *(const bf16x8*)(Bs + (wn * 64 + f * 16 + lr) * 64 + kk + lg * 8);
      #pragma unroll
      for (int i = 0; i < 4; ++i)
        #pragma unroll
        for (int j = 0; j < 4; ++j)
          acc[i][j] = __builtin_amdgcn_mfma_f32_16x16x32_bf16(a4[i], b4[j], acc[i][j], 0, 0, 0);
    }
    __syncthreads();
  }

  #pragma unroll
  for (int i = 0; i < 4; ++i) {
    const int mB = m0 + wm * 64 + i * 16 + lg * 4;
    #pragma unroll
    for (int j = 0; j < 4; ++j) {
      const int nn = n0 + wn * 64 + j * 16 + lr;
      const int brow = (EPI == 5) ? (((nn >> 6) << 7) + 64 + (nn & 63)) : nn;
      const float bs = bias ? bias[brow] : 0.0f;
      #pragma unroll
      for (int r = 0; r < 4; ++r) {
        const int m = mB + r;
        const float v = acc[i][j][r] * scale + bs;
        if (EPI == 0) {
          ((float*)Cout)[(long)bz * batchC + (long)m * ldc + nn] = v;
        } else if (EPI == 1) {
          ((u16*)Cout)[(long)bz * batchC + (long)m * ldc + nn] = f2bf(v);
        } else if (EPI == 2) { // (B,S,H*128) -> (B,H,S,128), swizzled d
          const int b = m >> 9, s = m & 511, h = nn >> 7, d = nn & 127;
          ((u16*)Cout)[(((long)(b * 16 + h) * 512 + s) << 7) + (d ^ ((s & 7) << 3))] = f2bf(v);
        } else if (EPI == 3) { // (B,S,H*128) -> (B,H,128,S), swizzled s
          const int b = m >> 9, s = m & 511, h = nn >> 7, d = nn & 127;
          ((u16*)Cout)[(((long)(b * 16 + h) * 128 + d) << 9) + (s ^ ((d & 7) << 3))] = f2bf(v);
        } else if (EPI == 5) { // k-half -> (B,H,S,128) dims 64..127, swizzled d
          const int b = m >> 9, s = m & 511, h = nn >> 6, d = 64 + (nn & 63);
          ((u16*)Cout)[(((long)(b * 16 + h) * 512 + s) << 7) + (d ^ ((s & 7) << 3))] = f2bf(v);
        }
      }
    }
  }
}

// ---------------- rope: read raw (4096 x 1024 f32), write swizzled bf16 into k_ws dims 0..63 ----------------
__global__ void rope_apply(const float* __restrict__ raw, u16* __restrict__ kws) {
  const int idx = blockIdx.x * 256 + threadIdx.x;   // < 4096*512
  const int i   = idx & 31;
  const int h   = (idx >> 5) & 15;
  const int row = idx >> 9;          // b*512 + s
  const int s   = row & 511;
  const int b   = row >> 9;
  const float x1 = raw[(long)row * 1024 + h * 64 + i];
  const float x2 = raw[(long)row * 1024 + h * 64 + 32 + i];
  const float invf = __powf(10000.0f, -(float)i * (1.0f / 32.0f));
  const float ang  = (float)s * invf;
  float sn, cs;
  __sincosf(ang, &sn, &cs);
  const long base = ((long)(b * 16 + h) * 512 + s) * 128;
  const int  msk  = (s & 7) << 3;
  kws[base + (i ^ msk)]        = f2bf(x1 * cs - x2 * sn);
  kws[base + ((32 + i) ^ msk)] = f2bf(x2 * cs + x1 * sn);
}

// ---------------- fused attention: scores + softmax + attn-write + PV ----------------
// grid (8 q-blocks, 128 bh); 256 threads = 4 waves, wave w owns q rows 16w..16w+16.
// q_ws/k_ws (B,H,S,128) and vT_ws (B,H,128,S), all bf16 with col ^= ((row&7)<<3) swizzle.
__launch_bounds__(256, 2)
__global__ void fused_attn(const u16* __restrict__ qg, const u16* __restrict__ kg,
                           const u16* __restrict__ vg, float* __restrict__ attn,
                           u16* __restrict__ ctx)
{
  __shared__ __align__(16) u16 Qs[64 * 128];
  __shared__ __align__(16) u16 KVs[128 * 128];
  __shared__ __align__(16) u16 Ps[64 * 128];
  const int tid = threadIdx.x, lane = tid & 63, w = tid >> 6;
  const int lr = lane & 15, lg = lane >> 4;
  const int q0 = blockIdx.x * 64;
  const int bh = blockIdx.y;
  const u16* Qg = qg + ((long)bh * 512 + q0) * 128;
  const u16* Kg = kg + (long)bh * 65536;
  const u16* Vg = vg + (long)bh * 65536;

  #pragma unroll
  for (int i = 0; i < 4; ++i)
    __builtin_amdgcn_global_load_lds((const AS1 void*)(Qg + tid * 8 + i * 2048),
                                     (AS3 void*)(Qs + tid * 8 + i * 2048), 16, 0, 0);

  f32x4 acc[32] = {};
  bf16x8 qa[4];
  const int arow = 16 * w + lr;
  const int amsk = (arow & 7) << 3;

  #pragma unroll
  for (int t = 0; t < 4; ++t) {
    #pragma unroll
    for (int i = 0; i < 8; ++i)
      __builtin_amdgcn_global_load_lds((const AS1 void*)(Kg + t * 16384 + tid * 8 + i * 2048),
                                       (AS3 void*)(KVs + tid * 8 + i * 2048), 16, 0, 0);
    __syncthreads();
    if (t == 0) {
      #pragma unroll
      for (int kc = 0; kc < 4; ++kc)
        qa[kc] = *(const bf16x8*)(Qs + arow * 128 + ((kc * 32 + lg * 8) ^ amsk));
    }
    #pragma unroll
    for (int nf = 0; nf < 8; ++nf) {
      const int n = nf * 16 + lr;
      const int nmsk = (n & 7) << 3;
      #pragma unroll
      for (int kc = 0; kc < 4; ++kc) {
        bf16x8 bb = *(const bf16x8*)(KVs + n * 128 + ((kc * 32 + lg * 8) ^ nmsk));
        acc[t * 8 + nf] = __builtin_amdgcn_mfma_f32_16x16x32_bf16(qa[kc], bb, acc[t * 8 + nf], 0, 0, 0);
      }
    }
    __syncthreads();
  }

  // wave-level softmax over full 512 cols (rows 16w+4lg+r, col = lane&15 + 16*frag)
  const float scale = 0.08838834764831845f;
  #pragma unroll
  for (int r = 0; r < 4; ++r) {
    float m_ = acc[0][r];
    #pragma unroll
    for (int f = 1; f < 32; ++f) m_ = fmaxf(m_, acc[f][r]);
    #pragma unroll
    for (int off = 8; off >= 1; off >>= 1) m_ = fmaxf(m_, __shfl_xor(m_, off));
    float s_ = 0.f;
    #pragma unroll
    for (int f = 0; f < 32; ++f) {
      const float e = __expf((acc[f][r] - m_) * scale);
      acc[f][r] = e; s_ += e;
    }
    #pragma unroll
    for (int off = 8; off >= 1; off >>= 1) s_ += __shfl_xor(s_, off);
    const float inv = 1.0f / s_;
    #pragma unroll
    for (int f = 0; f < 32; ++f) acc[f][r] *= inv;
  }

  // attn write: exact f32 from registers
  #pragma unroll
  for (int t = 0; t < 4; ++t)
    #pragma unroll
    for (int g = 0; g < 8; ++g)
      #pragma unroll
      for (int r = 0; r < 4; ++r)
        attn[((long)bh * 512 + q0 + 16 * w + 4 * lg + r) * 512 + t * 128 + g * 16 + lr] =
            acc[t * 8 + g][r];

  // PV: restage P (bf16, swizzled) per kv-tile, V tile -> KVs, accumulate ctx
  f32x4 ctxa[8] = {};
  #pragma unroll
  for (int t = 0; t < 4; ++t) {
    #pragma unroll
    for (int g = 0; g < 8; ++g)
      #pragma unroll
      for (int r = 0; r < 4; ++r) {
        const int row = 16 * w + 4 * lg + r;
        Ps[row * 128 + ((g * 16 + lr) ^ ((row & 7) << 3))] = f2bf(acc[t * 8 + g][r]);
      }
    #pragma unroll
    for (int i = 0; i < 8; ++i) {
      const int eo = tid * 8 + i * 2048;
      __builtin_amdgcn_global_load_lds((const AS1 void*)(Vg + (eo >> 7) * 512 + t * 128 + (eo & 127)),
                                       (AS3 void*)(KVs + eo), 16, 0, 0);
    }
    __syncthreads();
    bf16x8 pa[4];
    #pragma unroll
    for (int kc = 0; kc < 4; ++kc)
      pa[kc] = *(const bf16x8*)(Ps + arow * 128 + ((kc * 32 + lg * 8) ^ amsk));
    #pragma unroll
    for (int nf = 0; nf < 8; ++nf) {
      const int n = nf * 16 + lr;
      const int nmsk = (n & 7) << 3;
      #pragma unroll
      for (int kc = 0; kc < 4; ++kc) {
        bf16x8 vb = *(const bf16x8*)(KVs + n * 128 + ((kc * 32 + lg * 8) ^ nmsk));
        ctxa[nf] = __builtin_amdgcn_mfma_f32_16x16x32_bf16(pa[kc], vb, ctxa[nf], 0, 0, 0);
      }
    }
    __syncthreads();
  }

  const int b = bh >> 4, h = bh & 15;
  #pragma unroll
  for (int nf = 0; nf < 8; ++nf)
    #pragma unroll
    for (int r = 0; r < 4; ++r) {
      const int q = q0 + 16 * w + 4 * lg + r;
      ctx[(long)(b * 512 + q) * 2048 + h * 128 + nf * 16 + lr] = f2bf(ctxa[nf][r]);
    }
}

extern "C" void kernel_launch(void* const* d_in, const int* in_sizes, int n_in,
                              void* d_out, int out_size, void* d_ws, size_t ws_size,
                              hipStream_t stream)
{
  (void)in_sizes; (void)n_in; (void)out_size; (void)ws_size;
  const float* query  = (const float*)d_in[0];
  const float* kvin   = (const float*)d_in[1];
  const float* wq_w   = (const float*)d_in[2];
  const float* wq_b   = (const float*)d_in[3];
  const float* wdkv_w = (const float*)d_in[4];
  const float* wdkv_b = (const float*)d_in[5];
  const float* wupk_w = (const float*)d_in[6];
  const float* wupk_b = (const float*)d_in[7];
  const float* wupv_w = (const float*)d_in[8];
  const float* wupv_b = (const float*)d_in[9];
  const float* wkr_w  = (const float*)d_in[10];
  const float* wkr_b  = (const float*)d_in[11];
  const float* wo_w   = (const float*)d_in[12];
  const float* wo_b   = (const float*)d_in[13];

  float* out  = (float*)d_out;                 // (8,512,2048)
  float* attn = out + 8L * 512 * 2048;         // (8,16,512,512)

  u16* p = (u16*)d_ws;
  u16* query_bf = p; p += 8388608;
  u16* kv_bf    = p; p += 8388608;
  u16* wq_bf    = p; p += 4194304;
  u16* wdkv_bf  = p; p += 1048576;
  u16* wupk_bf  = p; p += 1048576;
  u16* wupv_bf  = p; p += 1048576;
  u16* wkr_bf   = p; p += 2097152;
  u16* wo_bf    = p; p += 4194304;
  u16* q_ws     = p; p += 8388608;   // (B,H,S,128) bf16, swizzled
  u16* ckv_bf   = p; p += 2097152;   // (4096,512) bf16
  u16* k_ws     = p; p += 8388608;   // (B,H,S,128) bf16, swizzled
  u16* vT_ws    = p; p += 8388608;   // (B,H,128,S) bf16, swizzled
  u16* ctx_ws   = p; p += 8388608;   // (B,S,H*128) bf16
  float* rope_raw = (float*)p;       // (4096,1024) f32

  auto cast = [&](const float* src, u16* dst, int n) {
    int n4 = n >> 2;
    cast_f32_to_bf16<<<dim3((n4 + 255) / 256), dim3(256), 0, stream>>>(src, dst, n4);
  };
  cast(query,  query_bf, 8388608);
  cast(kvin,   kv_bf,    8388608);
  cast(wq_w,   wq_bf,    4194304);
  cast(wdkv_w, wdkv_bf,  1048576);
  cast(wupk_w, wupk_bf,  1048576);
  cast(wupv_w, wupv_bf,  1048576);
  cast(wkr_w,  wkr_bf,   2097152);
  cast(wo_w,   wo_bf,    4194304);

  // c_kv = kv @ wdkv^T + b  -> bf16 (4096,512)
  gemm_nt<1><<<dim3(4, 32, 1), 256, 0, stream>>>(kv_bf, wdkv_bf, wdkv_b, ckv_bf,
      4096, 512, 2048, 2048, 2048, 512, 0, 0, 0, 1.0f);
  // k_up (dims 64..127 only) -> k_ws swizzled
  gemm_nt<5><<<dim3(8, 32, 1), 256, 0, stream>>>(ckv_bf, wupk_bf, wupk_b, k_ws,
      4096, 1024, 512, 512, 512, 0, 0, 0, 0, 1.0f);
  // v_up -> vT_ws swizzled
  gemm_nt<3><<<dim3(16, 32, 1), 256, 0, stream>>>(ckv_bf, wupv_bf, wupv_b, vT_ws,
      4096, 2048, 512, 512, 512, 0, 0, 0, 0, 1.0f);
  // k_rope raw = kv @ wkr^T + b -> f32 (4096,1024)
  gemm_nt<0><<<dim3(8, 32, 1), 256, 0, stream>>>(kv_bf, wkr_bf, wkr_b, rope_raw,
      4096, 1024, 2048, 2048, 2048, 1024, 0, 0, 0, 1.0f);
  // rope -> k_ws dims 0..63 (swizzled)
  rope_apply<<<dim3(8192), dim3(256), 0, stream>>>(rope_raw, k_ws);
  // q = query @ wq^T + b -> q_ws swizzled
  gemm_nt<2><<<dim3(16, 32, 1), 256, 0, stream>>>(query_bf, wq_bf, wq_b, q_ws,
      4096, 2048, 2048, 2048, 2048, 0, 0, 0, 0, 1.0f);
  // fused attention: scores + softmax + attn write + PV -> ctx_ws
  fused_attn<<<dim3(8, 128, 1), 256, 0, stream>>>(q_ws, k_ws, vT_ws, attn, ctx_ws);
  // out = ctx @ wo^T + b -> f32 (8,512,2048)
  gemm_nt<0><<<dim3(16, 32, 1), 256, 0, stream>>>(ctx_ws, wo_bf, wo_b, out,
      4096, 2048, 2048, 2048, 2048, 2048, 0, 0, 0, 1.0f);
}

// Round 3
// 367.552 us; speedup vs baseline: 1.1568x; 1.0411x over previous
//
#include <hip/hip_runtime.h>
#include <math.h>

typedef unsigned short u16;
typedef unsigned int   u32;
typedef __attribute__((ext_vector_type(4))) float f32x4;
typedef __attribute__((ext_vector_type(4))) u16   u16x4;
typedef __attribute__((ext_vector_type(8))) __bf16 bf16x8;

#define AS1 __attribute__((address_space(1)))
#define AS3 __attribute__((address_space(3)))

__device__ __forceinline__ u16 f2bf(float f) {
  u32 u = __builtin_bit_cast(u32, f);
  u += 0x7fffu + ((u >> 16) & 1u);   // round-to-nearest-even
  return (u16)(u >> 16);
}

// ---------------- fused cast f32 -> bf16, all 8 tensors in one launch ----------------
struct Cast8 {
  const float *i0,*i1,*i2,*i3,*i4,*i5,*i6,*i7;
  u16 *o0,*o1,*o2,*o3,*o4,*o5,*o6,*o7;
};
__global__ void cast_all(Cast8 c) {
  const int i = blockIdx.x * 256 + threadIdx.x;
  if (i >= 7602176) return;
  const float* src = c.i0; u16* dst = c.o0; int off = i;
  if (i >= 2097152 && i < 4194304) { src = c.i1; dst = c.o1; off = i - 2097152; }
  if (i >= 4194304 && i < 5242880) { src = c.i2; dst = c.o2; off = i - 4194304; }
  if (i >= 5242880 && i < 5505024) { src = c.i3; dst = c.o3; off = i - 5242880; }
  if (i >= 5505024 && i < 5767168) { src = c.i4; dst = c.o4; off = i - 5505024; }
  if (i >= 5767168 && i < 6029312) { src = c.i5; dst = c.o5; off = i - 5767168; }
  if (i >= 6029312 && i < 6553600) { src = c.i6; dst = c.o6; off = i - 6029312; }
  if (i >= 6553600)                { src = c.i7; dst = c.o7; off = i - 6553600; }
  f32x4 v = *(const f32x4*)(src + (long)off * 4);
  u16x4 o = { f2bf(v[0]), f2bf(v[1]), f2bf(v[2]), f2bf(v[3]) };
  *(u16x4*)(dst + (long)off * 4) = o;
}

// ---------------- old 128x128 NT GEMM (kept for c_kv: N=512) ----------------
template<int EPI>
__launch_bounds__(256, 2)
__global__ void gemm_nt(const u16* __restrict__ Ag, const u16* __restrict__ Bg,
                        const float* __restrict__ bias, void* __restrict__ Cout,
                        int M, int N, int K, int lda, int ldb, int ldc, float scale)
{
  __shared__ __align__(16) u16 As[128 * 64];
  __shared__ __align__(16) u16 Bs[128 * 64];
  const int tid  = threadIdx.x;
  const int lane = tid & 63;
  const int wid  = tid >> 6;
  const int wm = wid >> 1, wn = wid & 1;
  const int lr = lane & 15, lg = lane >> 4;
  const int m0 = blockIdx.y * 128, n0 = blockIdx.x * 128;

  f32x4 acc[4][4] = {};

  for (int k0 = 0; k0 < K; k0 += 64) {
    #pragma unroll
    for (int i = 0; i < 4; ++i) {
      const int eo = (wid * 64 + lane) * 8 + i * 2048;
      const int r = eo >> 6, c = eo & 63;
      __builtin_amdgcn_global_load_lds(
          (const AS1 void*)(Ag + (long)(m0 + r) * lda + (k0 + c)),
          (AS3 void*)(As + wid * 512 + i * 2048), 16, 0, 0);
    }
    #pragma unroll
    for (int i = 0; i < 4; ++i) {
      const int eo = (wid * 64 + lane) * 8 + i * 2048;
      const int r = eo >> 6, c = eo & 63;
      __builtin_amdgcn_global_load_lds(
          (const AS1 void*)(Bg + (long)(n0 + r) * ldb + (k0 + c)),
          (AS3 void*)(Bs + wid * 512 + i * 2048), 16, 0, 0);
    }
    __syncthreads();
    #pragma unroll
    for (int kk = 0; kk < 64; kk += 32) {
      bf16x8 a4[4], b4[4];
      #pragma unroll
      for (int f = 0; f < 4; ++f)
        a4[f] = *(const bf16x8*)(As + (wm * 64 + f * 16 + lr) * 64 + kk + lg * 8);
      #pragma unroll
      for (int f = 0; f < 4; ++f)
        b4[f] = *(const bf16x8*)(Bs + (wn * 64 + f * 16 + lr) * 64 + kk + lg * 8);
      #pragma unroll
      for (int i = 0; i < 4; ++i)
        #pragma unroll
        for (int j = 0; j < 4; ++j)
          acc[i][j] = __builtin_amdgcn_mfma_f32_16x16x32_bf16(a4[i], b4[j], acc[i][j], 0, 0, 0);
    }
    __syncthreads();
  }

  #pragma unroll
  for (int i = 0; i < 4; ++i) {
    const int mB = m0 + wm * 64 + i * 16 + lg * 4;
    #pragma unroll
    for (int j = 0; j < 4; ++j) {
      const int nn = n0 + wn * 64 + j * 16 + lr;
      const float bs = bias ? bias[nn] : 0.0f;
      #pragma unroll
      for (int r = 0; r < 4; ++r) {
        const int m = mB + r;
        const float v = acc[i][j][r] * scale + bs;
        if (EPI == 0) ((float*)Cout)[(long)m * ldc + nn] = v;
        else          ((u16*)Cout)[(long)m * ldc + nn] = f2bf(v);
      }
    }
  }
}

// ---------------- 256x256 8-phase NT GEMM (T1+T2+T3+T4+T5), runtime epilogue ----------------
// EPI: 0 f32 row-major; 2 bf16 (B,S,H*128)->(B,H,S,128) swizzled d;
//      3 bf16 ->(B,H,128,S) swizzled s; 5 bf16 k-half (B-row remap, d=64.. swizzled)
struct SubG {
  const u16* A; const u16* B; const float* bias; void* C;
  int Nt; int K; int lda; int ldb; int ldc; int EPI; int blk0;
};

#define MMQ(sh, bp, uh)                                                              \
  { _Pragma("unroll") for (int f_ = 0; f_ < 4; ++f_)                                 \
      _Pragma("unroll") for (int e_ = 0; e_ < 2; ++e_)                               \
        _Pragma("unroll") for (int k_ = 0; k_ < 2; ++k_)                             \
          acc[(sh)*4+f_][(uh)*2+e_] = __builtin_amdgcn_mfma_f32_16x16x32_bf16(       \
              aC[f_*2+k_], bp[e_*2+k_], acc[(sh)*4+f_][(uh)*2+e_], 0, 0, 0); }

__launch_bounds__(512, 2)
__global__ void gemm8(SubG g0, SubG g1, SubG g2, SubG g3, int ng)
{
  __shared__ __align__(16) u16 lds[65536];   // 128 KB: A buf0/1 @0/16384, B buf0/1 @32768/49152
  const int id   = blockIdx.x;
  const int tile = ((id & 7) * (gridDim.x >> 3)) + (id >> 3);   // bijective XCD swizzle (nwg%8==0)
  SubG g = g0;
  if (ng > 1 && tile >= g1.blk0) g = g1;
  if (ng > 2 && tile >= g2.blk0) g = g2;
  if (ng > 3 && tile >= g3.blk0) g = g3;
  const int local = tile - g.blk0;
  const int ty = local / g.Nt, tx = local - ty * g.Nt;
  const int m0 = ty << 8, n0 = tx << 8;

  const int tid = threadIdx.x, lane = tid & 63, w = tid >> 6;
  const int wm = w >> 2, wn = w & 3;
  const int lr = lane & 15, lg = lane >> 4;
  const int lda = g.lda, ldb = g.ldb;
  const bool remapB = (g.EPI == 5);
  const u16* Ag = g.A;
  const u16* Bg = g.B;

  // staging: linear LDS dest, inverse-swizzled global source (swizzle: colbyte ^= (row&7)<<4)
  const int srow = tid >> 3;                 // 0..63 row-within-64-row-slab
  const int scol = (((tid & 7) ^ (srow & 7)) << 3);
  const int dcol = (tid & 7) * 8;

  auto stageA = [&](int h, int t, int buf) {
    #pragma unroll
    for (int j = 0; j < 2; ++j) {
      const int rt = h * 128 + j * 64 + srow;
      __builtin_amdgcn_global_load_lds(
          (const AS1 void*)(Ag + (long)(m0 + rt) * lda + t * 64 + scol),
          (AS3 void*)(lds + buf * 16384 + rt * 64 + dcol), 16, 0, 0);
    }
  };
  auto stageB = [&](int h, int t, int buf) {
    #pragma unroll
    for (int j = 0; j < 2; ++j) {
      const int rt = h * 128 + j * 64 + srow;
      int nr = n0 + rt;
      if (remapB) nr = ((nr >> 6) << 7) + 64 + (nr & 63);
      __builtin_amdgcn_global_load_lds(
          (const AS1 void*)(Bg + (long)nr * ldb + t * 64 + scol),
          (AS3 void*)(lds + 32768 + buf * 16384 + rt * 64 + dcol), 16, 0, 0);
    }
  };

  f32x4 acc[8][4] = {};
  bf16x8 aC[8], bLo[4], bHi[4];
  const int rmask = (lr & 7) << 3;          // element-space read swizzle

  auto readA = [&](int s, int buf) {
    #pragma unroll
    for (int f = 0; f < 4; ++f)
      #pragma unroll
      for (int k = 0; k < 2; ++k) {
        const int R = wm * 128 + s * 64 + f * 16 + lr;
        aC[f*2+k] = *(const bf16x8*)(lds + buf * 16384 + R * 64 + ((k * 32 + lg * 8) ^ rmask));
      }
  };
  auto readB = [&](int s, int buf, bf16x8* bp) {
    #pragma unroll
    for (int f = 0; f < 2; ++f)
      #pragma unroll
      for (int k = 0; k < 2; ++k) {
        const int R = wn * 64 + s * 32 + f * 16 + lr;
        bp[f*2+k] = *(const bf16x8*)(lds + 32768 + buf * 16384 + R * 64 + ((k * 32 + lg * 8) ^ rmask));
      }
  };

  const int nIter = g.K >> 7;               // 2 K-tiles (BK=64) per iteration

  // prologue: stage tiles 0 (buf0) and 1 (buf1)
  stageA(0, 0, 0); stageA(1, 0, 0); stageB(0, 0, 0); stageB(1, 0, 0);
  stageA(0, 1, 1); stageA(1, 1, 1); stageB(0, 1, 1); stageB(1, 1, 1);
  asm volatile("s_waitcnt vmcnt(8)" ::: "memory");
  __builtin_amdgcn_s_barrier();

  for (int it = 0; it < nIter; ++it) {
    const int s0 = 2 * it + 2, s1 = 2 * it + 3;
    const bool st = (it < nIter - 1);
    // ---- phase 1: read A-half0,B-half0 of buf0; MFMA Q(m0,n0)
    readA(0, 0); readB(0, 0, bLo);
    __builtin_amdgcn_s_barrier();
    asm volatile("s_waitcnt lgkmcnt(0)" ::: "memory");
    __builtin_amdgcn_s_setprio(1); MMQ(0, bLo, 0); __builtin_amdgcn_s_setprio(0);
    __builtin_amdgcn_s_barrier();
    // ---- phase 2: read B-half1; MFMA Q(m0,n1)
    readB(1, 0, bHi);
    __builtin_amdgcn_s_barrier();
    asm volatile("s_waitcnt lgkmcnt(0)" ::: "memory");
    __builtin_amdgcn_s_setprio(1); MMQ(0, bHi, 1); __builtin_amdgcn_s_setprio(0);
    __builtin_amdgcn_s_barrier();
    // ---- phase 3: read A-half1; stage B0lo(next); MFMA Q(m1,n0)
    readA(1, 0);
    if (st) stageB(0, s0, 0);
    __builtin_amdgcn_s_barrier();
    asm volatile("s_waitcnt lgkmcnt(0)" ::: "memory");
    __builtin_amdgcn_s_setprio(1); MMQ(1, bLo, 0); __builtin_amdgcn_s_setprio(0);
    __builtin_amdgcn_s_barrier();
    // ---- phase 4: stage B0hi+A0lo(next); MFMA Q(m1,n1); counted vmcnt
    if (st) { stageB(1, s0, 0); stageA(0, s0, 0); }
    __builtin_amdgcn_s_barrier();
    __builtin_amdgcn_s_setprio(1); MMQ(1, bHi, 1); __builtin_amdgcn_s_setprio(0);
    if (it == nIter - 1) { asm volatile("s_waitcnt vmcnt(0)" ::: "memory"); }
    else                 { asm volatile("s_waitcnt vmcnt(6)" ::: "memory"); }
    __builtin_amdgcn_s_barrier();
    // ---- phase 5: buf1: read A-half0,B-half0; stage A0hi(next); MFMA Q(m0,n0)
    readA(0, 1); readB(0, 1, bLo);
    if (st) stageA(1, s0, 0);
    __builtin_amdgcn_s_barrier();
    asm volatile("s_waitcnt lgkmcnt(0)" ::: "memory");
    __builtin_amdgcn_s_setprio(1); MMQ(0, bLo, 0); __builtin_amdgcn_s_setprio(0);
    __builtin_amdgcn_s_barrier();
    // ---- phase 6: read B-half1; MFMA Q(m0,n1)
    readB(1, 1, bHi);
    __builtin_amdgcn_s_barrier();
    asm volatile("s_waitcnt lgkmcnt(0)" ::: "memory");
    __builtin_amdgcn_s_setprio(1); MMQ(0, bHi, 1); __builtin_amdgcn_s_setprio(0);
    __builtin_amdgcn_s_barrier();
    // ---- phase 7: read A-half1; stage B1lo(next); MFMA Q(m1,n0)
    readA(1, 1);
    if (st) stageB(0, s1, 1);
    __builtin_amdgcn_s_barrier();
    asm volatile("s_waitcnt lgkmcnt(0)" ::: "memory");
    __builtin_amdgcn_s_setprio(1); MMQ(1, bLo, 0); __builtin_amdgcn_s_setprio(0);
    __builtin_amdgcn_s_barrier();
    // ---- phase 8: stage B1hi+A1lo+A1hi(next); MFMA Q(m1,n1); counted vmcnt
    if (st) { stageB(1, s1, 1); stageA(0, s1, 1); stageA(1, s1, 1); }
    __builtin_amdgcn_s_barrier();
    __builtin_amdgcn_s_setprio(1); MMQ(1, bHi, 1); __builtin_amdgcn_s_setprio(0);
    if (st) { asm volatile("s_waitcnt vmcnt(8)" ::: "memory"); }
    __builtin_amdgcn_s_barrier();
  }

  // ---- epilogue
  #pragma unroll
  for (int mf = 0; mf < 8; ++mf) {
    const int Rb = m0 + wm * 128 + mf * 16 + lg * 4;
    #pragma unroll
    for (int nf = 0; nf < 4; ++nf) {
      const int nn = n0 + wn * 64 + nf * 16 + lr;
      const int bidx = (g.EPI == 5) ? (((nn >> 6) << 7) + 64 + (nn & 63)) : nn;
      const float bs = g.bias ? g.bias[bidx] : 0.0f;
      #pragma unroll
      for (int rr = 0; rr < 4; ++rr) {
        const int R = Rb + rr;
        const float v = acc[mf][nf][rr] + bs;
        if (g.EPI == 0) {
          ((float*)g.C)[(long)R * g.ldc + nn] = v;
        } else if (g.EPI == 2) {
          const int b = R >> 9, s2 = R & 511, h = nn >> 7, d = nn & 127;
          ((u16*)g.C)[(((long)(b * 16 + h) * 512 + s2) << 7) + (d ^ ((s2 & 7) << 3))] = f2bf(v);
        } else if (g.EPI == 3) {
          const int b = R >> 9, s2 = R & 511, h = nn >> 7, d = nn & 127;
          ((u16*)g.C)[(((long)(b * 16 + h) * 128 + d) << 9) + (s2 ^ ((d & 7) << 3))] = f2bf(v);
        } else { // EPI 5
          const int b = R >> 9, s2 = R & 511, h = nn >> 6, d = 64 + (nn & 63);
          ((u16*)g.C)[(((long)(b * 16 + h) * 512 + s2) << 7) + (d ^ ((s2 & 7) << 3))] = f2bf(v);
        }
      }
    }
  }
}

// ---------------- rope: read raw (4096 x 1024 f32), write swizzled bf16 into k_ws dims 0..63 ----------------
__global__ void rope_apply(const float* __restrict__ raw, u16* __restrict__ kws) {
  const int idx = blockIdx.x * 256 + threadIdx.x;   // < 4096*512
  const int i   = idx & 31;
  const int h   = (idx >> 5) & 15;
  const int row = idx >> 9;          // b*512 + s
  const int s   = row & 511;
  const int b   = row >> 9;
  const float x1 = raw[(long)row * 1024 + h * 64 + i];
  const float x2 = raw[(long)row * 1024 + h * 64 + 32 + i];
  const float invf = __powf(10000.0f, -(float)i * (1.0f / 32.0f));
  const float ang  = (float)s * invf;
  float sn, cs;
  __sincosf(ang, &sn, &cs);
  const long base = ((long)(b * 16 + h) * 512 + s) * 128;
  const int  msk  = (s & 7) << 3;
  kws[base + (i ^ msk)]        = f2bf(x1 * cs - x2 * sn);
  kws[base + ((32 + i) ^ msk)] = f2bf(x2 * cs + x1 * sn);
}

// ---------------- fused attention: scores + softmax + attn-write + PV ----------------
__launch_bounds__(256, 2)
__global__ void fused_attn(const u16* __restrict__ qg, const u16* __restrict__ kg,
                           const u16* __restrict__ vg, float* __restrict__ attn,
                           u16* __restrict__ ctx)
{
  __shared__ __align__(16) u16 Qs[64 * 128];
  __shared__ __align__(16) u16 KVs[128 * 128];
  __shared__ __align__(16) u16 Ps[64 * 128];
  const int tid = threadIdx.x, lane = tid & 63, w = tid >> 6;
  const int lr = lane & 15, lg = lane >> 4;
  const int q0 = blockIdx.x * 64;
  const int bh = blockIdx.y;
  const u16* Qg = qg + ((long)bh * 512 + q0) * 128;
  const u16* Kg = kg + (long)bh * 65536;
  const u16* Vg = vg + (long)bh * 65536;

  #pragma unroll
  for (int i = 0; i < 4; ++i)
    __builtin_amdgcn_global_load_lds((const AS1 void*)(Qg + tid * 8 + i * 2048),
                                     (AS3 void*)(Qs + tid * 8 + i * 2048), 16, 0, 0);

  f32x4 acc[32] = {};
  bf16x8 qa[4];
  const int arow = 16 * w + lr;
  const int amsk = (arow & 7) << 3;

  #pragma unroll
  for (int t = 0; t < 4; ++t) {
    #pragma unroll
    for (int i = 0; i < 8; ++i)
      __builtin_amdgcn_global_load_lds((const AS1 void*)(Kg + t * 16384 + tid * 8 + i * 2048),
                                       (AS3 void*)(KVs + tid * 8 + i * 2048), 16, 0, 0);
    __syncthreads();
    if (t == 0) {
      #pragma unroll
      for (int kc = 0; kc < 4; ++kc)
        qa[kc] = *(const bf16x8*)(Qs + arow * 128 + ((kc * 32 + lg * 8) ^ amsk));
    }
    #pragma unroll
    for (int nf = 0; nf < 8; ++nf) {
      const int n = nf * 16 + lr;
      const int nmsk = (n & 7) << 3;
      #pragma unroll
      for (int kc = 0; kc < 4; ++kc) {
        bf16x8 bb = *(const bf16x8*)(KVs + n * 128 + ((kc * 32 + lg * 8) ^ nmsk));
        acc[t * 8 + nf] = __builtin_amdgcn_mfma_f32_16x16x32_bf16(qa[kc], bb, acc[t * 8 + nf], 0, 0, 0);
      }
    }
    __syncthreads();
  }

  const float scale = 0.08838834764831845f;
  #pragma unroll
  for (int r = 0; r < 4; ++r) {
    float m_ = acc[0][r];
    #pragma unroll
    for (int f = 1; f < 32; ++f) m_ = fmaxf(m_, acc[f][r]);
    #pragma unroll
    for (int off = 8; off >= 1; off >>= 1) m_ = fmaxf(m_, __shfl_xor(m_, off));
    float s_ = 0.f;
    #pragma unroll
    for (int f = 0; f < 32; ++f) {
      const float e = __expf((acc[f][r] - m_) * scale);
      acc[f][r] = e; s_ += e;
    }
    #pragma unroll
    for (int off = 8; off >= 1; off >>= 1) s_ += __shfl_xor(s_, off);
    const float inv = 1.0f / s_;
    #pragma unroll
    for (int f = 0; f < 32; ++f) acc[f][r] *= inv;
  }

  #pragma unroll
  for (int t = 0; t < 4; ++t)
    #pragma unroll
    for (int g = 0; g < 8; ++g)
      #pragma unroll
      for (int r = 0; r < 4; ++r)
        attn[((long)bh * 512 + q0 + 16 * w + 4 * lg + r) * 512 + t * 128 + g * 16 + lr] =
            acc[t * 8 + g][r];

  f32x4 ctxa[8] = {};
  #pragma unroll
  for (int t = 0; t < 4; ++t) {
    #pragma unroll
    for (int g = 0; g < 8; ++g)
      #pragma unroll
      for (int r = 0; r < 4; ++r) {
        const int row = 16 * w + 4 * lg + r;
        Ps[row * 128 + ((g * 16 + lr) ^ ((row & 7) << 3))] = f2bf(acc[t * 8 + g][r]);
      }
    #pragma unroll
    for (int i = 0; i < 8; ++i) {
      const int eo = tid * 8 + i * 2048;
      __builtin_amdgcn_global_load_lds((const AS1 void*)(Vg + (eo >> 7) * 512 + t * 128 + (eo & 127)),
                                       (AS3 void*)(KVs + eo), 16, 0, 0);
    }
    __syncthreads();
    bf16x8 pa[4];
    #pragma unroll
    for (int kc = 0; kc < 4; ++kc)
      pa[kc] = *(const bf16x8*)(Ps + arow * 128 + ((kc * 32 + lg * 8) ^ amsk));
    #pragma unroll
    for (int nf = 0; nf < 8; ++nf) {
      const int n = nf * 16 + lr;
      const int nmsk = (n & 7) << 3;
      #pragma unroll
      for (int kc = 0; kc < 4; ++kc) {
        bf16x8 vb = *(const bf16x8*)(KVs + n * 128 + ((kc * 32 + lg * 8) ^ nmsk));
        ctxa[nf] = __builtin_amdgcn_mfma_f32_16x16x32_bf16(pa[kc], vb, ctxa[nf], 0, 0, 0);
      }
    }
    __syncthreads();
  }

  const int b = bh >> 4, h = bh & 15;
  #pragma unroll
  for (int nf = 0; nf < 8; ++nf)
    #pragma unroll
    for (int r = 0; r < 4; ++r) {
      const int q = q0 + 16 * w + 4 * lg + r;
      ctx[(long)(b * 512 + q) * 2048 + h * 128 + nf * 16 + lr] = f2bf(ctxa[nf][r]);
    }
}

extern "C" void kernel_launch(void* const* d_in, const int* in_sizes, int n_in,
                              void* d_out, int out_size, void* d_ws, size_t ws_size,
                              hipStream_t stream)
{
  (void)in_sizes; (void)n_in; (void)out_size; (void)ws_size;
  const float* query  = (const float*)d_in[0];
  const float* kvin   = (const float*)d_in[1];
  const float* wq_w   = (const float*)d_in[2];
  const float* wq_b   = (const float*)d_in[3];
  const float* wdkv_w = (const float*)d_in[4];
  const float* wdkv_b = (const float*)d_in[5];
  const float* wupk_w = (const float*)d_in[6];
  const float* wupk_b = (const float*)d_in[7];
  const float* wupv_w = (const float*)d_in[8];
  const float* wupv_b = (const float*)d_in[9];
  const float* wkr_w  = (const float*)d_in[10];
  const float* wkr_b  = (const float*)d_in[11];
  const float* wo_w   = (const float*)d_in[12];
  const float* wo_b   = (const float*)d_in[13];

  float* out  = (float*)d_out;                 // (8,512,2048)
  float* attn = out + 8L * 512 * 2048;         // (8,16,512,512)

  u16* p = (u16*)d_ws;
  u16* query_bf = p; p += 8388608;
  u16* kv_bf    = p; p += 8388608;
  u16* wq_bf    = p; p += 4194304;
  u16* wdkv_bf  = p; p += 1048576;
  u16* wupk_bf  = p; p += 1048576;
  u16* wupv_bf  = p; p += 1048576;
  u16* wkr_bf   = p; p += 2097152;
  u16* wo_bf    = p; p += 4194304;
  u16* q_ws     = p; p += 8388608;   // (B,H,S,128) bf16, swizzled
  u16* ckv_bf   = p; p += 2097152;   // (4096,512) bf16
  u16* k_ws     = p; p += 8388608;   // (B,H,S,128) bf16, swizzled
  u16* vT_ws    = p; p += 8388608;   // (B,H,128,S) bf16, swizzled
  u16* ctx_ws   = p; p += 8388608;   // (B,S,H*128) bf16
  float* rope_raw = (float*)p;       // (4096,1024) f32

  Cast8 c8 = { query, kvin, wq_w, wdkv_w, wupk_w, wupv_w, wkr_w, wo_w,
               query_bf, kv_bf, wq_bf, wdkv_bf, wupk_bf, wupv_bf, wkr_bf, wo_bf };
  cast_all<<<dim3(29696), dim3(256), 0, stream>>>(c8);

  // c_kv = kv @ wdkv^T + b  -> bf16 (4096,512)
  gemm_nt<1><<<dim3(4, 32, 1), 256, 0, stream>>>(kv_bf, wdkv_bf, wdkv_b, ckv_bf,
      4096, 512, 2048, 2048, 2048, 512, 1.0f);

  // mega-launch: k_up(EPI5) + v_up(EPI3) + k_rope(EPI0) + q(EPI2), 384 tiles of 256x256
  SubG gk = { ckv_bf,   wupk_bf, wupk_b, k_ws,     4, 512,  512,  512,  0,    5, 0   };
  SubG gv = { ckv_bf,   wupv_bf, wupv_b, vT_ws,    8, 512,  512,  512,  0,    3, 64  };
  SubG gr = { kv_bf,    wkr_bf,  wkr_b,  rope_raw, 4, 2048, 2048, 2048, 1024, 0, 192 };
  SubG gq = { query_bf, wq_bf,   wq_b,   q_ws,     8, 2048, 2048, 2048, 0,    2, 256 };
  gemm8<<<dim3(384), dim3(512), 0, stream>>>(gk, gv, gr, gq, 4);

  // rope -> k_ws dims 0..63 (swizzled)
  rope_apply<<<dim3(8192), dim3(256), 0, stream>>>(rope_raw, k_ws);

  // fused attention: scores + softmax + attn write + PV -> ctx_ws
  fused_attn<<<dim3(8, 128, 1), 256, 0, stream>>>(q_ws, k_ws, vT_ws, attn, ctx_ws);

  // out = ctx @ wo^T + b -> f32 (8,512,2048)
  SubG go = { ctx_ws, wo_bf, wo_b, out, 8, 2048, 2048, 2048, 2048, 0, 0 };
  gemm8<<<dim3(128), dim3(512), 0, stream>>>(go, go, go, go, 1);
}